// Round 10
// baseline (169.044 us; speedup 1.0000x reference)
//
#include <hip/hip_runtime.h>
#include <hip/hip_bf16.h>
#include <math.h>

#define BS 2048
#define STEPS 8
#define RB 8                  // valid rows per block (M=16 tile, rows 8-15 zero)
#define SX 136                // LDS stride (shorts) for 128-wide bf16 bufs  (dw%32==4 -> 2-way)
#define S2 264                // 256-wide
#define S6 72                 // 64-wide
#define SNB 132               // noise fp32 stride (dw)
#define ALPHA_C 60.0f
#define BETA_C 20.0f
#define EPSC_C 1e-8f

typedef __attribute__((ext_vector_type(8))) short frag_ab;   // 8 bf16
typedef __attribute__((ext_vector_type(4))) float frag_cd;   // 4 fp32

// ---- d_ws layout (bytes): 400 frags * 1024 B, then biases (1152 fp32)
#define BIAS_OFF_B  409600

// ---- fragment base offsets (units of one 1024-B frag)
#define FB_FW1 0
#define FB_FW2 64
#define FB_FW3 192
#define FB_KW  256
#define FB_KWT 288            // transposed kw (for v = wf @ kw^T)
#define FB_AM1 320
#define FB_AM2 336
#define FB_AM3 344
#define FB_AL1 360
#define FB_AL2 376
#define FB_AL3 384

// ---- bias float offsets
#define BO_FB1 0
#define BO_FB2 256
#define BO_FB3 512
#define BO_AMB1 640
#define BO_AMB2 704
#define BO_AMB3 768
#define BO_ALB1 896
#define BO_ALB2 960
#define BO_ALB3 1024

__device__ __forceinline__ short f2b(float x){ __hip_bfloat16 h=__float2bfloat16(x); return *reinterpret_cast<short*>(&h); }
__device__ __forceinline__ float b2f(short s){ __hip_bfloat16 h=*reinterpret_cast<__hip_bfloat16*>(&s); return __bfloat162float(h); }
__device__ __forceinline__ float sani(float x){ return isfinite(x)?x:0.f; }
// fast tanh: (1-e^{-2|x|})/(1+e^{-2|x|}) via v_exp_f32 + v_rcp_f32
__device__ __forceinline__ float fast_tanh(float x){
    float ax=fabsf(x);
    float u=__builtin_amdgcn_exp2f(-2.885390082f*ax);
    float t=(1.f-u)*__builtin_amdgcn_rcpf(1.f+u);
    return copysignf(t,x);
}
// fast softplus: max(x,0) + ln2*log2(1+2^{-|x|*log2e})
__device__ __forceinline__ float fast_softplus(float x){
    float ax=fabsf(x);
    float u=__builtin_amdgcn_exp2f(-1.442695041f*ax);
    return fmaxf(x,0.f) + 0.6931471806f*__builtin_amdgcn_logf(1.f+u);
}
// t = arange(9)/8: halfword[2]==0 iff fp32 storage; bf16(0.25)=0x3E80 otherwise
__device__ __forceinline__ bool is_f32_storage(const void* t){ return ((const unsigned short*)t)[2]==0; }
__device__ __forceinline__ float ldval(const void* p, size_t i, bool isf32){
    return isf32 ? ((const float*)p)[i] : __bfloat162float(((const __hip_bfloat16*)p)[i]);
}

struct Ptrs { const void* p[19]; };

// ---- single fused prep kernel: 400 frag-units (4/block, one per wave) + biases
// unit order matches FB_*: fw1(64) fw2(128) fw3(64) kw(32) kwT(32)
//                          am1(16) am2(8) am3(16) al1(16) al2(8) al3(16)
__global__ __launch_bounds__(256) void prep_kernel(Ptrs ps, const void* tp,
                                                   short* __restrict__ frags,
                                                   float* __restrict__ bdst){
    const bool isf32 = is_f32_storage(tp);
    const int b = blockIdx.x;
    if (b < 100){
        const int kit[11]={4,8,8,4,4,4,2,2,4,2,2};
        const int Nd [11]={256,256,128,128,128,64,64,128,64,64,128};
        const int src[11]={0,2,4,18,18,6,8,10,12,14,16};
        const int cnt[11]={64,128,64,32,32,16,8,16,16,8,16};
        const int w = threadIdx.x>>6, lane = threadIdx.x&63;
        const int u = b*4 + w;            // 0..399
        int mmi=0, acc=0;
        for (int q=0;q<11;++q){ if (u < acc+cnt[q]) { mmi=q; break; } acc+=cnt[q]; }
        int local=u-acc;
        int t=local/kit[mmi], i=local%kit[mmi];
        int n=t*16+(lane&15);
        int k0=i*32+(lane>>4)*8;
        frag_ab v;
        if (mmi==4){  // kwT: B[k][n] = kw[n][k] -> v[jj]=kw[n*128 + k0+jj] (contiguous)
            if (isf32){ const float* Wf=(const float*)ps.p[18];
                for(int j=0;j<8;++j) v[j]=f2b(Wf[(size_t)n*128+k0+j]); }
            else { const unsigned short* Wb=(const unsigned short*)ps.p[18];
                for(int j=0;j<8;++j) v[j]=(short)Wb[(size_t)n*128+k0+j]; }
        } else {
            int N=Nd[mmi];
            if (isf32){ const float* Wf=(const float*)ps.p[src[mmi]];
                for(int j=0;j<8;++j) v[j]=f2b(Wf[(size_t)(k0+j)*N+n]); }
            else { const unsigned short* Wb=(const unsigned short*)ps.p[src[mmi]];
                for(int j=0;j<8;++j) v[j]=(short)Wb[(size_t)(k0+j)*N+n]; }
        }
        *(frag_ab*)(frags + ((size_t)u*64 + lane)*8) = v;
    } else {
        const int srcs[9]={1,3,5,7,9,11,13,15,17};
        const int lens[9]={256,256,128,64,64,128,64,64,128};
        const int offs[9]={0,256,512,640,704,768,896,960,1024};
#pragma unroll
        for (int a=0;a<9;++a){
            const void* s=ps.p[srcs[a]];
            for (int i=threadIdx.x;i<lens[a];i+=256) bdst[offs[a]+i]=ldval(s,i,isf32);
        }
    }
}

// ---- fused 8-step ODE kernel: 256 blocks x 512 threads (8 waves), 8 rows/block
// Round-9 structure (fw1+kw in LDS, p/k/kwT in regs, 56 us) + three latency moves:
// 1. noise prefetched a FULL step ahead (5 barriers of cover vs 1).
// 2. rotating actor-weight prefetch: am1/al1 issued in E (->A), am2/al2 in A (->B),
//    am3/al3 in B (->C), kwT in C (->D): every L2 weight load issues one stage
//    before its consumer, hiding ~300cy L2 latency under MFMA work.
// 3. deferred frame store: stage A of step s stores frame s from ybuf (drains
//    under A's MFMAs); E only updates ybuf/xb; epilogue stores frame 8.
__global__ __launch_bounds__(512) void ode_kernel(const void* __restrict__ y0,
                                                  const void* __restrict__ noise,
                                                  const void* __restrict__ tp,
                                                  void* __restrict__ out,
                                                  const char* __restrict__ wsb){
    __shared__ __align__(16) short xb [16*SX];
    __shared__ __align__(16) short h1b[16*S2];
    __shared__ __align__(16) short h2b[16*S2];
    __shared__ __align__(16) short kb [16*SX];
    __shared__ __align__(16) short wfb[16*SX];
    __shared__ __align__(16) short a1b[16*S6];
    __shared__ __align__(16) short l1b[16*S6];
    __shared__ __align__(16) short a2b[16*S6];
    __shared__ __align__(16) short l2b[16*S6];
    __shared__ __align__(16) float fbuf[RB*128];
    __shared__ __align__(16) float gbuf[RB*128];
    __shared__ __align__(16) float ybuf[RB*128];
    __shared__ __align__(16) float nb[RB*SNB];
    __shared__ float knp[8*16], qwp[8*16], pwp[8*16];
    extern __shared__ __align__(16) short wlds[];   // 96KB: fw1 (64 frags) + kw (32 frags)
    short* fw1L = wlds;                 // frag f at fw1L + (f*64+lane)*8
    short* kwL  = wlds + 64*64*8;       // frag f at kwL  + (f*64+lane)*8

    const int tid=threadIdx.x, lane=tid&63, w=tid>>6;
    const int lm=lane&15, kq=(lane>>4)*8, m0=(lane>>4)*4;
    const bool lowhalf = (lane<32);       // output rows 0..7 (valid)
    const frag_ab* F=(const frag_ab*)wsb;
    const float* bias=(const float*)(wsb+BIAS_OFF_B);
    const bool isf32=is_f32_storage(tp);
    const float dt = ldval(tp,1,isf32)-ldval(tp,0,isf32);
    const int r0 = blockIdx.x*RB;
    const int mr0 = tid>>7, n0 = tid&127;            // noise/store elem 0 (idx=tid)
    const int mr1 = (tid+512)>>7, n1 = tid&127;      // noise/store elem 1 (idx=tid+512)
    const int th=w>>1; const bool isAm=((w&1)==0);
    const int fb1=isAm?FB_AM1:FB_AL1, fb2=isAm?FB_AM2:FB_AL2;
    const int bo1=isAm?BO_AMB1:BO_ALB1, bo2=isAm?BO_AMB2:BO_ALB2;

    // zero xb (incl. rows 8-15 and pads) so A rows 8-15 are always 0
    for (int i=tid;i<16*SX;i+=512) xb[i]=0;
    __syncthreads();
    // stage fw1+kw into LDS (once; reused all 8 steps)
    for (int idx=tid; idx<96*64; idx+=512){
        int u=idx>>6, l=idx&63;
        int su=(u<64)? u : (u+192);     // FB_FW1+u  or  FB_KW+(u-64)
        *(frag_ab*)(wlds + (size_t)idx*8) = F[(size_t)su*64+l];
    }
    // load y0 rows 0..7, write frame 0
    for (int idx=tid; idx<RB*128; idx+=512){
        int mr=idx>>7, n=idx&127;
        float v=ldval(y0,(size_t)(r0+mr)*128+n,isf32);
        ybuf[idx]=v; xb[mr*SX+n]=f2b(v);
        size_t o=(size_t)(r0+mr)*128+n;
        if (isf32) ((float*)out)[o]=v; else ((__hip_bfloat16*)out)[o]=__float2bfloat16(v);
    }
    // prologue prefetches: step-0 noise + am1/al1 for first stage A
    float nv0=ldval(noise,((size_t)0*BS + r0+mr0)*128 + n0, isf32);
    float nv1=ldval(noise,((size_t)0*BS + r0+mr1)*128 + n1, isf32);
    frag_ab pa1[4];
#pragma unroll
    for (int i=0;i<4;++i) pa1[i]=F[(fb1+th*4+i)*64+lane];
    __syncthreads();

    float mreg[4], sreg[4];

    for (int step=0; step<STEPS; ++step){
        float kreg[4];        // k values, set in A, used in C/D (same thread+reg mapping)
        frag_cd preg;         // p values, set in B, used in D (same thread+reg mapping)
        frag_ab pa2[2];       // am2/al2 prefetch (A -> B)
        frag_ab pm3[2], pl3[2]; // am3+al3 prefetch (B -> C)
        // ===== Stage A: frame-store(step) | h1 | k | am1/al1 (prefetched) | prefetch am2/al2 =====
        {
            // deferred frame store: ybuf holds y_step; store drains under A's MFMAs
            if (step>0){
                size_t ob=(size_t)step*BS*128;
                size_t o0=ob+(size_t)(r0+mr0)*128+n0, o1=ob+(size_t)(r0+mr1)*128+n1;
                if (isf32){ ((float*)out)[o0]=ybuf[tid]; ((float*)out)[o1]=ybuf[tid+512]; }
                else { ((__hip_bfloat16*)out)[o0]=__float2bfloat16(ybuf[tid]);
                       ((__hip_bfloat16*)out)[o1]=__float2bfloat16(ybuf[tid+512]); }
            }
#pragma unroll
            for (int i=0;i<2;++i) pa2[i]=F[(fb2+th*2+i)*64+lane];   // prefetch for stage B
            frag_cd a0={0,0,0,0}, a1={0,0,0,0};
            const int t0=2*w;
#pragma unroll
            for (int i=0;i<4;++i){
                frag_ab a=*(const frag_ab*)(xb + lm*SX + i*32 + kq);
                frag_ab b0=*(const frag_ab*)(fw1L + ((size_t)(t0*4+i)*64+lane)*8);
                frag_ab b1=*(const frag_ab*)(fw1L + ((size_t)((t0+1)*4+i)*64+lane)*8);
                a0=__builtin_amdgcn_mfma_f32_16x16x32_bf16(a,b0,a0,0,0,0);
                a1=__builtin_amdgcn_mfma_f32_16x16x32_bf16(a,b1,a1,0,0,0);
            }
            {
                int n=t0*16+lm; float bc=bias[BO_FB1+n];
#pragma unroll
                for(int r=0;r<4;++r) h1b[(m0+r)*S2+n]=f2b(fast_tanh(a0[r]+bc));
                n=(t0+1)*16+lm; bc=bias[BO_FB1+n];
#pragma unroll
                for(int r=0;r<4;++r) h1b[(m0+r)*S2+n]=f2b(fast_tanh(a1[r]+bc));
            }
            frag_cd ak={0,0,0,0};
#pragma unroll
            for (int i=0;i<4;++i){
                frag_ab a=*(const frag_ab*)(xb + lm*SX + i*32 + kq);
                frag_ab b=*(const frag_ab*)(kwL + ((size_t)(w*4+i)*64+lane)*8);
                ak=__builtin_amdgcn_mfma_f32_16x16x32_bf16(a,b,ak,0,0,0);
            }
            {
                int n=w*16+lm; float s[4];
#pragma unroll
                for(int r=0;r<4;++r){ float kv=fast_tanh(ak[r]); kreg[r]=kv; kb[(m0+r)*SX+n]=f2b(kv); s[r]=kv*kv; }
#pragma unroll
                for(int msk=1;msk<16;msk<<=1){
#pragma unroll
                    for(int r=0;r<4;++r) s[r]+=__shfl_xor(s[r],msk,64);
                }
                if (lm==0){
#pragma unroll
                    for(int r=0;r<4;++r) knp[w*16+m0+r]=s[r];
                }
            }
            {
                short* dst=isAm?a1b:l1b;
                frag_cd ac={0,0,0,0};
#pragma unroll
                for (int i=0;i<4;++i){
                    frag_ab a=*(const frag_ab*)(xb + lm*SX + i*32 + kq);
                    ac=__builtin_amdgcn_mfma_f32_16x16x32_bf16(a,pa1[i],ac,0,0,0);
                }
                int n=th*16+lm; float bc=bias[bo1+n];
#pragma unroll
                for(int r=0;r<4;++r) dst[(m0+r)*S6+n]=f2b(fmaxf(ac[r]+bc,0.f));
            }
        }
        __syncthreads();
        // ===== Stage B: nb<-nv; prefetch noise(step+1) + am3/al3 | h2 | p->preg | am2/al2 =====
        {
            nb[mr0*SNB+n0]=nv0;
            nb[mr1*SNB+n1]=nv1;
            if (step+1<STEPS){
                nv0=ldval(noise,((size_t)(step+1)*BS + r0+mr0)*128 + n0, isf32);
                nv1=ldval(noise,((size_t)(step+1)*BS + r0+mr1)*128 + n1, isf32);
            }
#pragma unroll
            for (int i=0;i<2;++i){ pm3[i]=F[(FB_AM3+w*2+i)*64+lane]; pl3[i]=F[(FB_AL3+w*2+i)*64+lane]; }
            frag_cd a0={0,0,0,0}, a1={0,0,0,0};
            const int t0=2*w;
#pragma unroll
            for (int i=0;i<8;++i){
                frag_ab a=*(const frag_ab*)(h1b + lm*S2 + i*32 + kq);
                a0=__builtin_amdgcn_mfma_f32_16x16x32_bf16(a,F[(FB_FW2+t0*8+i)*64+lane],a0,0,0,0);
                a1=__builtin_amdgcn_mfma_f32_16x16x32_bf16(a,F[(FB_FW2+(t0+1)*8+i)*64+lane],a1,0,0,0);
            }
            {
                int n=t0*16+lm; float bc=bias[BO_FB2+n];
#pragma unroll
                for(int r=0;r<4;++r) h2b[(m0+r)*S2+n]=f2b(fast_softplus(a0[r]+bc));
                n=(t0+1)*16+lm; bc=bias[BO_FB2+n];
#pragma unroll
                for(int r=0;r<4;++r) h2b[(m0+r)*S2+n]=f2b(fast_softplus(a1[r]+bc));
            }
            frag_cd ap={0,0,0,0};
#pragma unroll
            for (int i=0;i<4;++i){
                frag_ab a=*(const frag_ab*)(kb + lm*SX + i*32 + kq);
                frag_ab b=*(const frag_ab*)(kwL + ((size_t)(w*4+i)*64+lane)*8);
                ap=__builtin_amdgcn_mfma_f32_16x16x32_bf16(a,b,ap,0,0,0);
            }
            preg=ap;   // p stays in registers (consumed in stage D by the same thread/reg)
            {
                const short* srcb=isAm?a1b:l1b; short* dst=isAm?a2b:l2b;
                frag_cd ac={0,0,0,0};
#pragma unroll
                for (int i=0;i<2;++i){
                    frag_ab a=*(const frag_ab*)(srcb + lm*S6 + i*32 + kq);
                    ac=__builtin_amdgcn_mfma_f32_16x16x32_bf16(a,pa2[i],ac,0,0,0);
                }
                int n=th*16+lm; float bc=bias[bo2+n];
#pragma unroll
                for(int r=0;r<4;++r) dst[(m0+r)*S6+n]=f2b(fmaxf(ac[r]+bc,0.f));
            }
        }
        __syncthreads();
        // ===== Stage C: prefetch kwT | f (fw3) + wf | am3 -> mreg | al3 -> sreg (prefetched) =====
        frag_ab pkt[4];
        {
#pragma unroll
            for (int i=0;i<4;++i) pkt[i]=F[(FB_KWT+w*4+i)*64+lane];   // L2 latency hides under C's MFMAs
            frag_cd af={0,0,0,0};
#pragma unroll
            for (int i=0;i<8;++i){
                frag_ab a=*(const frag_ab*)(h2b + lm*S2 + i*32 + kq);
                af=__builtin_amdgcn_mfma_f32_16x16x32_bf16(a,F[(FB_FW3+w*8+i)*64+lane],af,0,0,0);
            }
            {
                int n=w*16+lm; float bc=bias[BO_FB3+n];
#pragma unroll
                for(int r=0;r<4;++r){
                    float fv=af[r]+bc;
                    if (lowhalf) fbuf[(m0+r)*128+n]=fv;
                    float kv=kreg[r];
                    wfb[(m0+r)*SX+n]=f2b((1.f-kv*kv)*fv);
                }
            }
            frag_cd am={0,0,0,0};
#pragma unroll
            for (int i=0;i<2;++i){
                frag_ab a=*(const frag_ab*)(a2b + lm*S6 + i*32 + kq);
                am=__builtin_amdgcn_mfma_f32_16x16x32_bf16(a,pm3[i],am,0,0,0);
            }
            { int n=w*16+lm; float bc=bias[BO_AMB3+n];
#pragma unroll
              for(int r=0;r<4;++r) mreg[r]=sani(fast_tanh(am[r]+bc)); }
            frag_cd al={0,0,0,0};
#pragma unroll
            for (int i=0;i<2;++i){
                frag_ab a=*(const frag_ab*)(l2b + lm*S6 + i*32 + kq);
                al=__builtin_amdgcn_mfma_f32_16x16x32_bf16(a,pl3[i],al,0,0,0);
            }
            { int n=w*16+lm; float bc=bias[BO_ALB3+n];
#pragma unroll
              for(int r=0;r<4;++r) sreg[r]=fast_softplus(sani(al[r]+bc)); }
        }
        __syncthreads();
        // ===== Stage D: v = wf @ kw^T (prefetched) -> ||Jf||^2 partial | g, wg, p.wg =====
        {
            frag_cd aq={0,0,0,0};
#pragma unroll
            for (int i=0;i<4;++i){
                frag_ab a=*(const frag_ab*)(wfb + lm*SX + i*32 + kq);
                aq=__builtin_amdgcn_mfma_f32_16x16x32_bf16(a,pkt[i],aq,0,0,0);
            }
            int n=w*16+lm;
            float s1[4], s3[4];
#pragma unroll
            for(int r=0;r<4;++r){
                s1[r]=aq[r]*aq[r];                     // v_n^2
                float eps = lowhalf ? nb[(m0+r)*SNB+n] : 0.f;
                float gv=fast_tanh(mreg[r]+sreg[r]*eps);
                if (lowhalf) gbuf[(m0+r)*128+n]=gv;
                float kv=kreg[r];
                float wg=(1.f-kv*kv)*gv;
                s3[r]=preg[r]*wg;
            }
#pragma unroll
            for(int msk=1;msk<16;msk<<=1){
#pragma unroll
                for(int r=0;r<4;++r){ s1[r]+=__shfl_xor(s1[r],msk,64); s3[r]+=__shfl_xor(s3[r],msk,64); }
            }
            if (lm==0){
#pragma unroll
                for(int r=0;r<4;++r){ qwp[w*16+m0+r]=s1[r]; pwp[w*16+m0+r]=s3[r]; }
            }
        }
        __syncthreads();
        // ===== Stage E: mask + Euler update (no global store) | prefetch am1/al1 for next A =====
        {
#pragma unroll
            for (int i=0;i<4;++i) pa1[i]=F[(fb1+th*4+i)*64+lane];   // prefetch for next stage A
            for (int idx=tid; idx<RB*128; idx+=512){
                int mr=idx>>7;
                float kn2=0.f, jf2=0.f, kdjg=0.f;
#pragma unroll
                for (int wv=0;wv<8;++wv){
                    kn2 +=knp[wv*16+mr];
                    jf2 +=qwp[wv*16+mr];
                    kdjg+=pwp[wv*16+mr];
                }
                kn2=fmaxf(kn2,0.f); jf2=fmaxf(jf2,0.f);
                float kn=sqrtf(kn2);
                float kn9=kn2*kn2*kn2*kn2*kn;
                float kn10=kn2*kn2*kn2*kn2*kn2;
                float c1=sqrtf(jf2)-ALPHA_C*kn9;
                float c2=kdjg-BETA_C*kn10;
                float mask=((c1>EPSC_C)||(c2<-EPSC_C))?0.5f:1.0f;
                float dx=fbuf[idx]+gbuf[idx];
                float yn=ybuf[idx]+mask*dx*dt;
                ybuf[idx]=yn; xb[mr*SX+(idx&127)]=f2b(yn);
            }
        }
        __syncthreads();
    }
    // epilogue: store final frame (y_STEPS) from ybuf
    {
        size_t ob=(size_t)STEPS*BS*128;
        size_t o0=ob+(size_t)(r0+mr0)*128+n0, o1=ob+(size_t)(r0+mr1)*128+n1;
        if (isf32){ ((float*)out)[o0]=ybuf[tid]; ((float*)out)[o1]=ybuf[tid+512]; }
        else { ((__hip_bfloat16*)out)[o0]=__float2bfloat16(ybuf[tid]);
               ((__hip_bfloat16*)out)[o1]=__float2bfloat16(ybuf[tid+512]); }
    }
}

extern "C" void kernel_launch(void* const* d_in, const int* in_sizes, int n_in,
                              void* d_out, int out_size, void* d_ws, size_t ws_size,
                              hipStream_t stream) {
    Ptrs ps;
    for (int i=0;i<19;++i) ps.p[i]=d_in[3+i];
    const void* tp=d_in[1];
    char* wsb=(char*)d_ws;
    float* bdst=(float*)(wsb+BIAS_OFF_B);

    prep_kernel<<<101,256,0,stream>>>(ps, tp, (short*)wsb, bdst);
    ode_kernel<<<BS/RB,512,96*1024,stream>>>(d_in[0], d_in[2], tp, d_out, wsb);
}

// Round 11
// 159.982 us; speedup vs baseline: 1.0566x; 1.0566x over previous
//
#include <hip/hip_runtime.h>
#include <hip/hip_bf16.h>
#include <math.h>

#define BS 2048
#define STEPS 8
#define RB 8                  // valid rows per block (M=16 tile, rows 8-15 zero)
#define SX 136                // LDS stride (shorts) for 128-wide bf16 bufs  (dw%32==4 -> 2-way)
#define S2 264                // 256-wide
#define S6 72                 // 64-wide
#define SNB 132               // noise fp32 stride (dw)
#define ALPHA_C 60.0f
#define BETA_C 20.0f
#define EPSC_C 1e-8f

typedef __attribute__((ext_vector_type(8))) short frag_ab;   // 8 bf16
typedef __attribute__((ext_vector_type(4))) float frag_cd;   // 4 fp32

// ---- d_ws layout (bytes): 400 frags * 1024 B, then biases (1152 fp32)
#define BIAS_OFF_B  409600

// ---- fragment base offsets (units of one 1024-B frag)
#define FB_FW1 0
#define FB_FW2 64
#define FB_FW3 192
#define FB_KW  256
#define FB_KWT 288            // transposed kw (for v = wf @ kw^T)
#define FB_AM1 320
#define FB_AM2 336
#define FB_AM3 344
#define FB_AL1 360
#define FB_AL2 376
#define FB_AL3 384

// ---- bias float offsets
#define BO_FB1 0
#define BO_FB2 256
#define BO_FB3 512
#define BO_AMB1 640
#define BO_AMB2 704
#define BO_AMB3 768
#define BO_ALB1 896
#define BO_ALB2 960
#define BO_ALB3 1024

__device__ __forceinline__ short f2b(float x){ __hip_bfloat16 h=__float2bfloat16(x); return *reinterpret_cast<short*>(&h); }
__device__ __forceinline__ float b2f(short s){ __hip_bfloat16 h=*reinterpret_cast<__hip_bfloat16*>(&s); return __bfloat162float(h); }
__device__ __forceinline__ float sani(float x){ return isfinite(x)?x:0.f; }
// fast tanh: (1-e^{-2|x|})/(1+e^{-2|x|}) via v_exp_f32 + v_rcp_f32
__device__ __forceinline__ float fast_tanh(float x){
    float ax=fabsf(x);
    float u=__builtin_amdgcn_exp2f(-2.885390082f*ax);
    float t=(1.f-u)*__builtin_amdgcn_rcpf(1.f+u);
    return copysignf(t,x);
}
// fast softplus: max(x,0) + ln2*log2(1+2^{-|x|*log2e})
__device__ __forceinline__ float fast_softplus(float x){
    float ax=fabsf(x);
    float u=__builtin_amdgcn_exp2f(-1.442695041f*ax);
    return fmaxf(x,0.f) + 0.6931471806f*__builtin_amdgcn_logf(1.f+u);
}
// t = arange(9)/8: halfword[2]==0 iff fp32 storage; bf16(0.25)=0x3E80 otherwise
__device__ __forceinline__ bool is_f32_storage(const void* t){ return ((const unsigned short*)t)[2]==0; }
__device__ __forceinline__ float ldval(const void* p, size_t i, bool isf32){
    return isf32 ? ((const float*)p)[i] : __bfloat162float(((const __hip_bfloat16*)p)[i]);
}

struct Ptrs { const void* p[19]; };

// ---- single fused prep kernel: 400 frag-units (4/block, one per wave) + biases
// unit order matches FB_*: fw1(64) fw2(128) fw3(64) kw(32) kwT(32)
//                          am1(16) am2(8) am3(16) al1(16) al2(8) al3(16)
__global__ __launch_bounds__(256) void prep_kernel(Ptrs ps, const void* tp,
                                                   short* __restrict__ frags,
                                                   float* __restrict__ bdst){
    const bool isf32 = is_f32_storage(tp);
    const int b = blockIdx.x;
    if (b < 100){
        const int kit[11]={4,8,8,4,4,4,2,2,4,2,2};
        const int Nd [11]={256,256,128,128,128,64,64,128,64,64,128};
        const int src[11]={0,2,4,18,18,6,8,10,12,14,16};
        const int cnt[11]={64,128,64,32,32,16,8,16,16,8,16};
        const int w = threadIdx.x>>6, lane = threadIdx.x&63;
        const int u = b*4 + w;            // 0..399
        int mmi=0, acc=0;
        for (int q=0;q<11;++q){ if (u < acc+cnt[q]) { mmi=q; break; } acc+=cnt[q]; }
        int local=u-acc;
        int t=local/kit[mmi], i=local%kit[mmi];
        int n=t*16+(lane&15);
        int k0=i*32+(lane>>4)*8;
        frag_ab v;
        if (mmi==4){  // kwT: B[k][n] = kw[n][k] -> v[jj]=kw[n*128 + k0+jj] (contiguous)
            if (isf32){ const float* Wf=(const float*)ps.p[18];
                for(int j=0;j<8;++j) v[j]=f2b(Wf[(size_t)n*128+k0+j]); }
            else { const unsigned short* Wb=(const unsigned short*)ps.p[18];
                for(int j=0;j<8;++j) v[j]=(short)Wb[(size_t)n*128+k0+j]; }
        } else {
            int N=Nd[mmi];
            if (isf32){ const float* Wf=(const float*)ps.p[src[mmi]];
                for(int j=0;j<8;++j) v[j]=f2b(Wf[(size_t)(k0+j)*N+n]); }
            else { const unsigned short* Wb=(const unsigned short*)ps.p[src[mmi]];
                for(int j=0;j<8;++j) v[j]=(short)Wb[(size_t)(k0+j)*N+n]; }
        }
        *(frag_ab*)(frags + ((size_t)u*64 + lane)*8) = v;
    } else {
        const int srcs[9]={1,3,5,7,9,11,13,15,17};
        const int lens[9]={256,256,128,64,64,128,64,64,128};
        const int offs[9]={0,256,512,640,704,768,896,960,1024};
#pragma unroll
        for (int a=0;a<9;++a){
            const void* s=ps.p[srcs[a]];
            for (int i=threadIdx.x;i<lens[a];i+=256) bdst[offs[a]+i]=ldval(s,i,isf32);
        }
    }
}

// ---- fused 8-step ODE kernel: 256 blocks x 512 threads (8 waves), 8 rows/block
// Round-9 structure EXACTLY (fw1+kw in LDS, p/k/kwT in regs, 56 us proven) plus
// two register-neutral latency moves (round 10's rotating weight prefetch spilled
// at +40 live VGPRs -> reverted; headroom above round-9's live set is ~16 regs):
// 1. noise prefetched a FULL step ahead (nv0/nv1 = 2 VGPRs, 4 barriers of cover).
// 2. deferred frame store: stage A of step s re-reads ybuf (LDS) and stores frame
//    s; the store drain hides under A's MFMAs instead of E's short tail. Epilogue
//    stores frame 8. Zero extra live registers across barriers.
__global__ __launch_bounds__(512) void ode_kernel(const void* __restrict__ y0,
                                                  const void* __restrict__ noise,
                                                  const void* __restrict__ tp,
                                                  void* __restrict__ out,
                                                  const char* __restrict__ wsb){
    __shared__ __align__(16) short xb [16*SX];
    __shared__ __align__(16) short h1b[16*S2];
    __shared__ __align__(16) short h2b[16*S2];
    __shared__ __align__(16) short kb [16*SX];
    __shared__ __align__(16) short wfb[16*SX];
    __shared__ __align__(16) short a1b[16*S6];
    __shared__ __align__(16) short l1b[16*S6];
    __shared__ __align__(16) short a2b[16*S6];
    __shared__ __align__(16) short l2b[16*S6];
    __shared__ __align__(16) float fbuf[RB*128];
    __shared__ __align__(16) float gbuf[RB*128];
    __shared__ __align__(16) float ybuf[RB*128];
    __shared__ __align__(16) float nb[RB*SNB];
    __shared__ float knp[8*16], qwp[8*16], pwp[8*16];
    extern __shared__ __align__(16) short wlds[];   // 96KB: fw1 (64 frags) + kw (32 frags)
    short* fw1L = wlds;                 // frag f at fw1L + (f*64+lane)*8
    short* kwL  = wlds + 64*64*8;       // frag f at kwL  + (f*64+lane)*8

    const int tid=threadIdx.x, lane=tid&63, w=tid>>6;
    const int lm=lane&15, kq=(lane>>4)*8, m0=(lane>>4)*4;
    const bool lowhalf = (lane<32);       // output rows 0..7 (valid)
    const frag_ab* F=(const frag_ab*)wsb;
    const float* bias=(const float*)(wsb+BIAS_OFF_B);
    const bool isf32=is_f32_storage(tp);
    const float dt = ldval(tp,1,isf32)-ldval(tp,0,isf32);
    const int r0 = blockIdx.x*RB;
    const int mr0 = tid>>7, n0 = tid&127;            // noise/store elem 0 (idx=tid)
    const int mr1 = (tid+512)>>7, n1 = tid&127;      // noise/store elem 1 (idx=tid+512)

    // zero xb (incl. rows 8-15 and pads) so A rows 8-15 are always 0
    for (int i=tid;i<16*SX;i+=512) xb[i]=0;
    __syncthreads();
    // stage fw1+kw into LDS (once; reused all 8 steps)
    for (int idx=tid; idx<96*64; idx+=512){
        int u=idx>>6, l=idx&63;
        int su=(u<64)? u : (u+192);     // FB_FW1+u  or  FB_KW+(u-64)
        *(frag_ab*)(wlds + (size_t)idx*8) = F[(size_t)su*64+l];
    }
    // load y0 rows 0..7, write frame 0
    for (int idx=tid; idx<RB*128; idx+=512){
        int mr=idx>>7, n=idx&127;
        float v=ldval(y0,(size_t)(r0+mr)*128+n,isf32);
        ybuf[idx]=v; xb[mr*SX+n]=f2b(v);
        size_t o=(size_t)(r0+mr)*128+n;
        if (isf32) ((float*)out)[o]=v; else ((__hip_bfloat16*)out)[o]=__float2bfloat16(v);
    }
    // prologue prefetch: step-0 noise
    float nv0=ldval(noise,((size_t)0*BS + r0+mr0)*128 + n0, isf32);
    float nv1=ldval(noise,((size_t)0*BS + r0+mr1)*128 + n1, isf32);
    __syncthreads();

    float mreg[4], sreg[4];

    for (int step=0; step<STEPS; ++step){
        float kreg[4];        // k values, set in A, used in C/D (same thread+reg mapping)
        frag_cd preg;         // p values, set in B, used in D (same thread+reg mapping)
        // ===== Stage A: frame-store(step) | h1 | k | am1/al1 =====
        {
            // deferred frame store: ybuf holds y_step; store drains under A's MFMAs
            if (step>0){
                size_t ob=(size_t)step*BS*128;
                size_t o0=ob+(size_t)(r0+mr0)*128+n0, o1=ob+(size_t)(r0+mr1)*128+n1;
                if (isf32){ ((float*)out)[o0]=ybuf[tid]; ((float*)out)[o1]=ybuf[tid+512]; }
                else { ((__hip_bfloat16*)out)[o0]=__float2bfloat16(ybuf[tid]);
                       ((__hip_bfloat16*)out)[o1]=__float2bfloat16(ybuf[tid+512]); }
            }
            frag_cd a0={0,0,0,0}, a1={0,0,0,0};
            const int t0=2*w;
#pragma unroll
            for (int i=0;i<4;++i){
                frag_ab a=*(const frag_ab*)(xb + lm*SX + i*32 + kq);
                frag_ab b0=*(const frag_ab*)(fw1L + ((size_t)(t0*4+i)*64+lane)*8);
                frag_ab b1=*(const frag_ab*)(fw1L + ((size_t)((t0+1)*4+i)*64+lane)*8);
                a0=__builtin_amdgcn_mfma_f32_16x16x32_bf16(a,b0,a0,0,0,0);
                a1=__builtin_amdgcn_mfma_f32_16x16x32_bf16(a,b1,a1,0,0,0);
            }
            {
                int n=t0*16+lm; float bc=bias[BO_FB1+n];
#pragma unroll
                for(int r=0;r<4;++r) h1b[(m0+r)*S2+n]=f2b(fast_tanh(a0[r]+bc));
                n=(t0+1)*16+lm; bc=bias[BO_FB1+n];
#pragma unroll
                for(int r=0;r<4;++r) h1b[(m0+r)*S2+n]=f2b(fast_tanh(a1[r]+bc));
            }
            frag_cd ak={0,0,0,0};
#pragma unroll
            for (int i=0;i<4;++i){
                frag_ab a=*(const frag_ab*)(xb + lm*SX + i*32 + kq);
                frag_ab b=*(const frag_ab*)(kwL + ((size_t)(w*4+i)*64+lane)*8);
                ak=__builtin_amdgcn_mfma_f32_16x16x32_bf16(a,b,ak,0,0,0);
            }
            {
                int n=w*16+lm; float s[4];
#pragma unroll
                for(int r=0;r<4;++r){ float kv=fast_tanh(ak[r]); kreg[r]=kv; kb[(m0+r)*SX+n]=f2b(kv); s[r]=kv*kv; }
#pragma unroll
                for(int msk=1;msk<16;msk<<=1){
#pragma unroll
                    for(int r=0;r<4;++r) s[r]+=__shfl_xor(s[r],msk,64);
                }
                if (lm==0){
#pragma unroll
                    for(int r=0;r<4;++r) knp[w*16+m0+r]=s[r];
                }
            }
            {
                const int th=w>>1; const bool isAm=((w&1)==0);
                const int fb=isAm?FB_AM1:FB_AL1, bo=isAm?BO_AMB1:BO_ALB1;
                short* dst=isAm?a1b:l1b;
                frag_cd ac={0,0,0,0};
#pragma unroll
                for (int i=0;i<4;++i){
                    frag_ab a=*(const frag_ab*)(xb + lm*SX + i*32 + kq);
                    ac=__builtin_amdgcn_mfma_f32_16x16x32_bf16(a,F[(fb+th*4+i)*64+lane],ac,0,0,0);
                }
                int n=th*16+lm; float bc=bias[bo+n];
#pragma unroll
                for(int r=0;r<4;++r) dst[(m0+r)*S6+n]=f2b(fmaxf(ac[r]+bc,0.f));
            }
        }
        __syncthreads();
        // ===== Stage B: nb<-nv; prefetch noise(step+1) | h2 | p->preg | am2/al2 =====
        {
            nb[mr0*SNB+n0]=nv0;
            nb[mr1*SNB+n1]=nv1;
            if (step+1<STEPS){
                nv0=ldval(noise,((size_t)(step+1)*BS + r0+mr0)*128 + n0, isf32);
                nv1=ldval(noise,((size_t)(step+1)*BS + r0+mr1)*128 + n1, isf32);
            }
            frag_cd a0={0,0,0,0}, a1={0,0,0,0};
            const int t0=2*w;
#pragma unroll
            for (int i=0;i<8;++i){
                frag_ab a=*(const frag_ab*)(h1b + lm*S2 + i*32 + kq);
                a0=__builtin_amdgcn_mfma_f32_16x16x32_bf16(a,F[(FB_FW2+t0*8+i)*64+lane],a0,0,0,0);
                a1=__builtin_amdgcn_mfma_f32_16x16x32_bf16(a,F[(FB_FW2+(t0+1)*8+i)*64+lane],a1,0,0,0);
            }
            {
                int n=t0*16+lm; float bc=bias[BO_FB2+n];
#pragma unroll
                for(int r=0;r<4;++r) h2b[(m0+r)*S2+n]=f2b(fast_softplus(a0[r]+bc));
                n=(t0+1)*16+lm; bc=bias[BO_FB2+n];
#pragma unroll
                for(int r=0;r<4;++r) h2b[(m0+r)*S2+n]=f2b(fast_softplus(a1[r]+bc));
            }
            frag_cd ap={0,0,0,0};
#pragma unroll
            for (int i=0;i<4;++i){
                frag_ab a=*(const frag_ab*)(kb + lm*SX + i*32 + kq);
                frag_ab b=*(const frag_ab*)(kwL + ((size_t)(w*4+i)*64+lane)*8);
                ap=__builtin_amdgcn_mfma_f32_16x16x32_bf16(a,b,ap,0,0,0);
            }
            preg=ap;   // p stays in registers (consumed in stage D by the same thread/reg)
            {
                const int th=w>>1; const bool isAm=((w&1)==0);
                const int fb=isAm?FB_AM2:FB_AL2, bo=isAm?BO_AMB2:BO_ALB2;
                const short* srcb=isAm?a1b:l1b; short* dst=isAm?a2b:l2b;
                frag_cd ac={0,0,0,0};
#pragma unroll
                for (int i=0;i<2;++i){
                    frag_ab a=*(const frag_ab*)(srcb + lm*S6 + i*32 + kq);
                    ac=__builtin_amdgcn_mfma_f32_16x16x32_bf16(a,F[(fb+th*2+i)*64+lane],ac,0,0,0);
                }
                int n=th*16+lm; float bc=bias[bo+n];
#pragma unroll
                for(int r=0;r<4;++r) dst[(m0+r)*S6+n]=f2b(fmaxf(ac[r]+bc,0.f));
            }
        }
        __syncthreads();
        // ===== Stage C: prefetch kwT -> regs | f (fw3, tile w) + wf | am3 -> mreg | al3 -> sreg =====
        frag_ab pkt[4];
        {
#pragma unroll
            for (int i=0;i<4;++i) pkt[i]=F[(FB_KWT+w*4+i)*64+lane];   // L2 latency hides under C's MFMAs
            frag_cd af={0,0,0,0};
#pragma unroll
            for (int i=0;i<8;++i){
                frag_ab a=*(const frag_ab*)(h2b + lm*S2 + i*32 + kq);
                af=__builtin_amdgcn_mfma_f32_16x16x32_bf16(a,F[(FB_FW3+w*8+i)*64+lane],af,0,0,0);
            }
            {
                int n=w*16+lm; float bc=bias[BO_FB3+n];
#pragma unroll
                for(int r=0;r<4;++r){
                    float fv=af[r]+bc;
                    if (lowhalf) fbuf[(m0+r)*128+n]=fv;
                    float kv=kreg[r];
                    wfb[(m0+r)*SX+n]=f2b((1.f-kv*kv)*fv);
                }
            }
            frag_cd am={0,0,0,0};
#pragma unroll
            for (int i=0;i<2;++i){
                frag_ab a=*(const frag_ab*)(a2b + lm*S6 + i*32 + kq);
                am=__builtin_amdgcn_mfma_f32_16x16x32_bf16(a,F[(FB_AM3+w*2+i)*64+lane],am,0,0,0);
            }
            { int n=w*16+lm; float bc=bias[BO_AMB3+n];
#pragma unroll
              for(int r=0;r<4;++r) mreg[r]=sani(fast_tanh(am[r]+bc)); }
            frag_cd al={0,0,0,0};
#pragma unroll
            for (int i=0;i<2;++i){
                frag_ab a=*(const frag_ab*)(l2b + lm*S6 + i*32 + kq);
                al=__builtin_amdgcn_mfma_f32_16x16x32_bf16(a,F[(FB_AL3+w*2+i)*64+lane],al,0,0,0);
            }
            { int n=w*16+lm; float bc=bias[BO_ALB3+n];
#pragma unroll
              for(int r=0;r<4;++r) sreg[r]=fast_softplus(sani(al[r]+bc)); }
        }
        __syncthreads();
        // ===== Stage D: v = wf @ kw^T (prefetched) -> ||Jf||^2 partial | g, wg, p.wg =====
        {
            frag_cd aq={0,0,0,0};
#pragma unroll
            for (int i=0;i<4;++i){
                frag_ab a=*(const frag_ab*)(wfb + lm*SX + i*32 + kq);
                aq=__builtin_amdgcn_mfma_f32_16x16x32_bf16(a,pkt[i],aq,0,0,0);
            }
            int n=w*16+lm;
            float s1[4], s3[4];
#pragma unroll
            for(int r=0;r<4;++r){
                s1[r]=aq[r]*aq[r];                     // v_n^2
                float eps = lowhalf ? nb[(m0+r)*SNB+n] : 0.f;
                float gv=fast_tanh(mreg[r]+sreg[r]*eps);
                if (lowhalf) gbuf[(m0+r)*128+n]=gv;
                float kv=kreg[r];
                float wg=(1.f-kv*kv)*gv;
                s3[r]=preg[r]*wg;
            }
#pragma unroll
            for(int msk=1;msk<16;msk<<=1){
#pragma unroll
                for(int r=0;r<4;++r){ s1[r]+=__shfl_xor(s1[r],msk,64); s3[r]+=__shfl_xor(s3[r],msk,64); }
            }
            if (lm==0){
#pragma unroll
                for(int r=0;r<4;++r){ qwp[w*16+m0+r]=s1[r]; pwp[w*16+m0+r]=s3[r]; }
            }
        }
        __syncthreads();
        // ===== Stage E: mask + Euler update (no global store) =====
        {
            for (int idx=tid; idx<RB*128; idx+=512){
                int mr=idx>>7;
                float kn2=0.f, jf2=0.f, kdjg=0.f;
#pragma unroll
                for (int wv=0;wv<8;++wv){
                    kn2 +=knp[wv*16+mr];
                    jf2 +=qwp[wv*16+mr];
                    kdjg+=pwp[wv*16+mr];
                }
                kn2=fmaxf(kn2,0.f); jf2=fmaxf(jf2,0.f);
                float kn=sqrtf(kn2);
                float kn9=kn2*kn2*kn2*kn2*kn;
                float kn10=kn2*kn2*kn2*kn2*kn2;
                float c1=sqrtf(jf2)-ALPHA_C*kn9;
                float c2=kdjg-BETA_C*kn10;
                float mask=((c1>EPSC_C)||(c2<-EPSC_C))?0.5f:1.0f;
                float dx=fbuf[idx]+gbuf[idx];
                float yn=ybuf[idx]+mask*dx*dt;
                ybuf[idx]=yn; xb[mr*SX+(idx&127)]=f2b(yn);
            }
        }
        __syncthreads();
    }
    // epilogue: store final frame (y_STEPS) from ybuf
    {
        size_t ob=(size_t)STEPS*BS*128;
        size_t o0=ob+(size_t)(r0+mr0)*128+n0, o1=ob+(size_t)(r0+mr1)*128+n1;
        if (isf32){ ((float*)out)[o0]=ybuf[tid]; ((float*)out)[o1]=ybuf[tid+512]; }
        else { ((__hip_bfloat16*)out)[o0]=__float2bfloat16(ybuf[tid]);
               ((__hip_bfloat16*)out)[o1]=__float2bfloat16(ybuf[tid+512]); }
    }
}

extern "C" void kernel_launch(void* const* d_in, const int* in_sizes, int n_in,
                              void* d_out, int out_size, void* d_ws, size_t ws_size,
                              hipStream_t stream) {
    Ptrs ps;
    for (int i=0;i<19;++i) ps.p[i]=d_in[3+i];
    const void* tp=d_in[1];
    char* wsb=(char*)d_ws;
    float* bdst=(float*)(wsb+BIAS_OFF_B);

    prep_kernel<<<101,256,0,stream>>>(ps, tp, (short*)wsb, bdst);
    ode_kernel<<<BS/RB,512,96*1024,stream>>>(d_in[0], d_in[2], tp, d_out, wsb);
}

// Round 12
// 157.400 us; speedup vs baseline: 1.0740x; 1.0164x over previous
//
#include <hip/hip_runtime.h>
#include <hip/hip_bf16.h>
#include <math.h>

#define BS 2048
#define STEPS 8
#define RB 8                  // valid rows per block (M=16 tile, rows 8-15 zero)
#define SX 136                // LDS stride (shorts) for 128-wide bf16 bufs  (dw%32==4 -> 2-way)
#define S2 264                // 256-wide
#define S6 72                 // 64-wide
#define SNB 132               // noise fp32 stride (dw)
#define ALPHA_C 60.0f
#define BETA_C 20.0f
#define EPSC_C 1e-8f

typedef __attribute__((ext_vector_type(8))) short frag_ab;   // 8 bf16
typedef __attribute__((ext_vector_type(4))) float frag_cd;   // 4 fp32

// ---- d_ws layout (bytes): 400 frags * 1024 B, then biases (1152 fp32)
#define BIAS_OFF_B  409600

// ---- fragment base offsets (units of one 1024-B frag)
#define FB_FW1 0
#define FB_FW2 64
#define FB_FW3 192
#define FB_KW  256
#define FB_KWT 288            // transposed kw (for v = wf @ kw^T)
#define FB_AM1 320
#define FB_AM2 336
#define FB_AM3 344
#define FB_AL1 360
#define FB_AL2 376
#define FB_AL3 384

// ---- bias float offsets
#define BO_FB1 0
#define BO_FB2 256
#define BO_FB3 512
#define BO_AMB1 640
#define BO_AMB2 704
#define BO_AMB3 768
#define BO_ALB1 896
#define BO_ALB2 960
#define BO_ALB3 1024

__device__ __forceinline__ short f2b(float x){ __hip_bfloat16 h=__float2bfloat16(x); return *reinterpret_cast<short*>(&h); }
__device__ __forceinline__ float b2f(short s){ __hip_bfloat16 h=*reinterpret_cast<__hip_bfloat16*>(&s); return __bfloat162float(h); }
__device__ __forceinline__ float sani(float x){ return isfinite(x)?x:0.f; }
// fast tanh: (1-e^{-2|x|})/(1+e^{-2|x|}) via v_exp_f32 + v_rcp_f32
__device__ __forceinline__ float fast_tanh(float x){
    float ax=fabsf(x);
    float u=__builtin_amdgcn_exp2f(-2.885390082f*ax);
    float t=(1.f-u)*__builtin_amdgcn_rcpf(1.f+u);
    return copysignf(t,x);
}
// fast softplus: max(x,0) + ln2*log2(1+2^{-|x|*log2e})
__device__ __forceinline__ float fast_softplus(float x){
    float ax=fabsf(x);
    float u=__builtin_amdgcn_exp2f(-1.442695041f*ax);
    return fmaxf(x,0.f) + 0.6931471806f*__builtin_amdgcn_logf(1.f+u);
}
// t = arange(9)/8: halfword[2]==0 iff fp32 storage; bf16(0.25)=0x3E80 otherwise
__device__ __forceinline__ bool is_f32_storage(const void* t){ return ((const unsigned short*)t)[2]==0; }
__device__ __forceinline__ float ldval(const void* p, size_t i, bool isf32){
    return isf32 ? ((const float*)p)[i] : __bfloat162float(((const __hip_bfloat16*)p)[i]);
}

struct Ptrs { const void* p[19]; };

// ---- single fused prep kernel: 400 frag-units (4/block, one per wave) + biases
// unit order matches FB_*: fw1(64) fw2(128) fw3(64) kw(32) kwT(32)
//                          am1(16) am2(8) am3(16) al1(16) al2(8) al3(16)
__global__ __launch_bounds__(256) void prep_kernel(Ptrs ps, const void* tp,
                                                   short* __restrict__ frags,
                                                   float* __restrict__ bdst){
    const bool isf32 = is_f32_storage(tp);
    const int b = blockIdx.x;
    if (b < 100){
        const int kit[11]={4,8,8,4,4,4,2,2,4,2,2};
        const int Nd [11]={256,256,128,128,128,64,64,128,64,64,128};
        const int src[11]={0,2,4,18,18,6,8,10,12,14,16};
        const int cnt[11]={64,128,64,32,32,16,8,16,16,8,16};
        const int w = threadIdx.x>>6, lane = threadIdx.x&63;
        const int u = b*4 + w;            // 0..399
        int mmi=0, acc=0;
        for (int q=0;q<11;++q){ if (u < acc+cnt[q]) { mmi=q; break; } acc+=cnt[q]; }
        int local=u-acc;
        int t=local/kit[mmi], i=local%kit[mmi];
        int n=t*16+(lane&15);
        int k0=i*32+(lane>>4)*8;
        frag_ab v;
        if (mmi==4){  // kwT: B[k][n] = kw[n][k] -> v[jj]=kw[n*128 + k0+jj] (contiguous)
            if (isf32){ const float* Wf=(const float*)ps.p[18];
                for(int j=0;j<8;++j) v[j]=f2b(Wf[(size_t)n*128+k0+j]); }
            else { const unsigned short* Wb=(const unsigned short*)ps.p[18];
                for(int j=0;j<8;++j) v[j]=(short)Wb[(size_t)n*128+k0+j]; }
        } else {
            int N=Nd[mmi];
            if (isf32){ const float* Wf=(const float*)ps.p[src[mmi]];
                for(int j=0;j<8;++j) v[j]=f2b(Wf[(size_t)(k0+j)*N+n]); }
            else { const unsigned short* Wb=(const unsigned short*)ps.p[src[mmi]];
                for(int j=0;j<8;++j) v[j]=(short)Wb[(size_t)(k0+j)*N+n]; }
        }
        *(frag_ab*)(frags + ((size_t)u*64 + lane)*8) = v;
    } else {
        const int srcs[9]={1,3,5,7,9,11,13,15,17};
        const int lens[9]={256,256,128,64,64,128,64,64,128};
        const int offs[9]={0,256,512,640,704,768,896,960,1024};
#pragma unroll
        for (int a=0;a<9;++a){
            const void* s=ps.p[srcs[a]];
            for (int i=threadIdx.x;i<lens[a];i+=256) bdst[offs[a]+i]=ldval(s,i,isf32);
        }
    }
}

// ---- fused 8-step ODE kernel: 256 blocks x 512 threads (8 waves), 8 rows/block
// Round-9 structure EXACTLY (fw1+kw in 96KB LDS, p/k/kwT in regs, noise loaded at
// A-top -> nb in B [1-barrier live range], 56.0 us proven) plus ONLY the
// register-neutral deferred frame store:
//   stage E no longer stores `out`; stage A of step s re-reads ybuf (LDS) and
//   stores frame s (drains under A's MFMAs); epilogue stores frame 8.
// Round-10/11 lesson: ANY added cross-barrier register state (rotating weight
// prefetch +40 regs, or noise live across 4 barriers) spills at the 128-VGPR
// edge -> FETCH/WRITE rise. Tripwire: WRITE > 11.5 MB means spill -> revert.
__global__ __launch_bounds__(512) void ode_kernel(const void* __restrict__ y0,
                                                  const void* __restrict__ noise,
                                                  const void* __restrict__ tp,
                                                  void* __restrict__ out,
                                                  const char* __restrict__ wsb){
    __shared__ __align__(16) short xb [16*SX];
    __shared__ __align__(16) short h1b[16*S2];
    __shared__ __align__(16) short h2b[16*S2];
    __shared__ __align__(16) short kb [16*SX];
    __shared__ __align__(16) short wfb[16*SX];
    __shared__ __align__(16) short a1b[16*S6];
    __shared__ __align__(16) short l1b[16*S6];
    __shared__ __align__(16) short a2b[16*S6];
    __shared__ __align__(16) short l2b[16*S6];
    __shared__ __align__(16) float fbuf[RB*128];
    __shared__ __align__(16) float gbuf[RB*128];
    __shared__ __align__(16) float ybuf[RB*128];
    __shared__ __align__(16) float nb[RB*SNB];
    __shared__ float knp[8*16], qwp[8*16], pwp[8*16];
    extern __shared__ __align__(16) short wlds[];   // 96KB: fw1 (64 frags) + kw (32 frags)
    short* fw1L = wlds;                 // frag f at fw1L + (f*64+lane)*8
    short* kwL  = wlds + 64*64*8;       // frag f at kwL  + (f*64+lane)*8

    const int tid=threadIdx.x, lane=tid&63, w=tid>>6;
    const int lm=lane&15, kq=(lane>>4)*8, m0=(lane>>4)*4;
    const bool lowhalf = (lane<32);       // output rows 0..7 (valid)
    const frag_ab* F=(const frag_ab*)wsb;
    const float* bias=(const float*)(wsb+BIAS_OFF_B);
    const bool isf32=is_f32_storage(tp);
    const float dt = ldval(tp,1,isf32)-ldval(tp,0,isf32);
    const int r0 = blockIdx.x*RB;
    const int mr0 = tid>>7, n0 = tid&127;            // noise/store elem 0 (idx=tid)
    const int mr1 = (tid+512)>>7, n1 = tid&127;      // noise/store elem 1 (idx=tid+512)

    // zero xb (incl. rows 8-15 and pads) so A rows 8-15 are always 0
    for (int i=tid;i<16*SX;i+=512) xb[i]=0;
    __syncthreads();
    // stage fw1+kw into LDS (once; reused all 8 steps)
    for (int idx=tid; idx<96*64; idx+=512){
        int u=idx>>6, l=idx&63;
        int su=(u<64)? u : (u+192);     // FB_FW1+u  or  FB_KW+(u-64)
        *(frag_ab*)(wlds + (size_t)idx*8) = F[(size_t)su*64+l];
    }
    // load y0 rows 0..7, write frame 0
    for (int idx=tid; idx<RB*128; idx+=512){
        int mr=idx>>7, n=idx&127;
        float v=ldval(y0,(size_t)(r0+mr)*128+n,isf32);
        ybuf[idx]=v; xb[mr*SX+n]=f2b(v);
        size_t o=(size_t)(r0+mr)*128+n;
        if (isf32) ((float*)out)[o]=v; else ((__hip_bfloat16*)out)[o]=__float2bfloat16(v);
    }
    __syncthreads();

    float mreg[4], sreg[4];

    for (int step=0; step<STEPS; ++step){
        float nv0, nv1;       // noise prefetch (A -> nb in B, 1-barrier live range)
        float kreg[4];        // k values, set in A, used in C/D (same thread+reg mapping)
        frag_cd preg;         // p values, set in B, used in D (same thread+reg mapping)
        // ===== Stage A: frame-store(step) | noise prefetch | h1 | k | am1/al1 =====
        {
            // deferred frame store: ybuf holds y_step; store drains under A's MFMAs
            if (step>0){
                size_t ob=(size_t)step*BS*128;
                size_t o0=ob+(size_t)(r0+mr0)*128+n0, o1=ob+(size_t)(r0+mr1)*128+n1;
                if (isf32){ ((float*)out)[o0]=ybuf[tid]; ((float*)out)[o1]=ybuf[tid+512]; }
                else { ((__hip_bfloat16*)out)[o0]=__float2bfloat16(ybuf[tid]);
                       ((__hip_bfloat16*)out)[o1]=__float2bfloat16(ybuf[tid+512]); }
            }
            // prefetch this step's noise into regs (HBM latency hides under MFMAs)
            nv0=ldval(noise,((size_t)step*BS + r0+mr0)*128 + n0, isf32);
            nv1=ldval(noise,((size_t)step*BS + r0+mr1)*128 + n1, isf32);
            frag_cd a0={0,0,0,0}, a1={0,0,0,0};
            const int t0=2*w;
#pragma unroll
            for (int i=0;i<4;++i){
                frag_ab a=*(const frag_ab*)(xb + lm*SX + i*32 + kq);
                frag_ab b0=*(const frag_ab*)(fw1L + ((size_t)(t0*4+i)*64+lane)*8);
                frag_ab b1=*(const frag_ab*)(fw1L + ((size_t)((t0+1)*4+i)*64+lane)*8);
                a0=__builtin_amdgcn_mfma_f32_16x16x32_bf16(a,b0,a0,0,0,0);
                a1=__builtin_amdgcn_mfma_f32_16x16x32_bf16(a,b1,a1,0,0,0);
            }
            {
                int n=t0*16+lm; float bc=bias[BO_FB1+n];
#pragma unroll
                for(int r=0;r<4;++r) h1b[(m0+r)*S2+n]=f2b(fast_tanh(a0[r]+bc));
                n=(t0+1)*16+lm; bc=bias[BO_FB1+n];
#pragma unroll
                for(int r=0;r<4;++r) h1b[(m0+r)*S2+n]=f2b(fast_tanh(a1[r]+bc));
            }
            frag_cd ak={0,0,0,0};
#pragma unroll
            for (int i=0;i<4;++i){
                frag_ab a=*(const frag_ab*)(xb + lm*SX + i*32 + kq);
                frag_ab b=*(const frag_ab*)(kwL + ((size_t)(w*4+i)*64+lane)*8);
                ak=__builtin_amdgcn_mfma_f32_16x16x32_bf16(a,b,ak,0,0,0);
            }
            {
                int n=w*16+lm; float s[4];
#pragma unroll
                for(int r=0;r<4;++r){ float kv=fast_tanh(ak[r]); kreg[r]=kv; kb[(m0+r)*SX+n]=f2b(kv); s[r]=kv*kv; }
#pragma unroll
                for(int msk=1;msk<16;msk<<=1){
#pragma unroll
                    for(int r=0;r<4;++r) s[r]+=__shfl_xor(s[r],msk,64);
                }
                if (lm==0){
#pragma unroll
                    for(int r=0;r<4;++r) knp[w*16+m0+r]=s[r];
                }
            }
            {
                const int th=w>>1; const bool isAm=((w&1)==0);
                const int fb=isAm?FB_AM1:FB_AL1, bo=isAm?BO_AMB1:BO_ALB1;
                short* dst=isAm?a1b:l1b;
                frag_cd ac={0,0,0,0};
#pragma unroll
                for (int i=0;i<4;++i){
                    frag_ab a=*(const frag_ab*)(xb + lm*SX + i*32 + kq);
                    ac=__builtin_amdgcn_mfma_f32_16x16x32_bf16(a,F[(fb+th*4+i)*64+lane],ac,0,0,0);
                }
                int n=th*16+lm; float bc=bias[bo+n];
#pragma unroll
                for(int r=0;r<4;++r) dst[(m0+r)*S6+n]=f2b(fmaxf(ac[r]+bc,0.f));
            }
        }
        __syncthreads();
        // ===== Stage B: nb<-nv | h2 (fw2) | p = k@kw (kw from LDS) -> preg | am2/al2 =====
        {
            nb[mr0*SNB+n0]=nv0;
            nb[mr1*SNB+n1]=nv1;
            frag_cd a0={0,0,0,0}, a1={0,0,0,0};
            const int t0=2*w;
#pragma unroll
            for (int i=0;i<8;++i){
                frag_ab a=*(const frag_ab*)(h1b + lm*S2 + i*32 + kq);
                a0=__builtin_amdgcn_mfma_f32_16x16x32_bf16(a,F[(FB_FW2+t0*8+i)*64+lane],a0,0,0,0);
                a1=__builtin_amdgcn_mfma_f32_16x16x32_bf16(a,F[(FB_FW2+(t0+1)*8+i)*64+lane],a1,0,0,0);
            }
            {
                int n=t0*16+lm; float bc=bias[BO_FB2+n];
#pragma unroll
                for(int r=0;r<4;++r) h2b[(m0+r)*S2+n]=f2b(fast_softplus(a0[r]+bc));
                n=(t0+1)*16+lm; bc=bias[BO_FB2+n];
#pragma unroll
                for(int r=0;r<4;++r) h2b[(m0+r)*S2+n]=f2b(fast_softplus(a1[r]+bc));
            }
            frag_cd ap={0,0,0,0};
#pragma unroll
            for (int i=0;i<4;++i){
                frag_ab a=*(const frag_ab*)(kb + lm*SX + i*32 + kq);
                frag_ab b=*(const frag_ab*)(kwL + ((size_t)(w*4+i)*64+lane)*8);
                ap=__builtin_amdgcn_mfma_f32_16x16x32_bf16(a,b,ap,0,0,0);
            }
            preg=ap;   // p stays in registers (consumed in stage D by the same thread/reg)
            {
                const int th=w>>1; const bool isAm=((w&1)==0);
                const int fb=isAm?FB_AM2:FB_AL2, bo=isAm?BO_AMB2:BO_ALB2;
                const short* srcb=isAm?a1b:l1b; short* dst=isAm?a2b:l2b;
                frag_cd ac={0,0,0,0};
#pragma unroll
                for (int i=0;i<2;++i){
                    frag_ab a=*(const frag_ab*)(srcb + lm*S6 + i*32 + kq);
                    ac=__builtin_amdgcn_mfma_f32_16x16x32_bf16(a,F[(fb+th*2+i)*64+lane],ac,0,0,0);
                }
                int n=th*16+lm; float bc=bias[bo+n];
#pragma unroll
                for(int r=0;r<4;++r) dst[(m0+r)*S6+n]=f2b(fmaxf(ac[r]+bc,0.f));
            }
        }
        __syncthreads();
        // ===== Stage C: prefetch kwT -> regs | f (fw3, tile w) + wf | am3 -> mreg | al3 -> sreg =====
        frag_ab pkt[4];
        {
#pragma unroll
            for (int i=0;i<4;++i) pkt[i]=F[(FB_KWT+w*4+i)*64+lane];   // L2 latency hides under C's MFMAs
            frag_cd af={0,0,0,0};
#pragma unroll
            for (int i=0;i<8;++i){
                frag_ab a=*(const frag_ab*)(h2b + lm*S2 + i*32 + kq);
                af=__builtin_amdgcn_mfma_f32_16x16x32_bf16(a,F[(FB_FW3+w*8+i)*64+lane],af,0,0,0);
            }
            {
                int n=w*16+lm; float bc=bias[BO_FB3+n];
#pragma unroll
                for(int r=0;r<4;++r){
                    float fv=af[r]+bc;
                    if (lowhalf) fbuf[(m0+r)*128+n]=fv;
                    float kv=kreg[r];
                    wfb[(m0+r)*SX+n]=f2b((1.f-kv*kv)*fv);
                }
            }
            frag_cd am={0,0,0,0};
#pragma unroll
            for (int i=0;i<2;++i){
                frag_ab a=*(const frag_ab*)(a2b + lm*S6 + i*32 + kq);
                am=__builtin_amdgcn_mfma_f32_16x16x32_bf16(a,F[(FB_AM3+w*2+i)*64+lane],am,0,0,0);
            }
            { int n=w*16+lm; float bc=bias[BO_AMB3+n];
#pragma unroll
              for(int r=0;r<4;++r) mreg[r]=sani(fast_tanh(am[r]+bc)); }
            frag_cd al={0,0,0,0};
#pragma unroll
            for (int i=0;i<2;++i){
                frag_ab a=*(const frag_ab*)(l2b + lm*S6 + i*32 + kq);
                al=__builtin_amdgcn_mfma_f32_16x16x32_bf16(a,F[(FB_AL3+w*2+i)*64+lane],al,0,0,0);
            }
            { int n=w*16+lm; float bc=bias[BO_ALB3+n];
#pragma unroll
              for(int r=0;r<4;++r) sreg[r]=fast_softplus(sani(al[r]+bc)); }
        }
        __syncthreads();
        // ===== Stage D: v = wf @ kw^T (prefetched) -> ||Jf||^2 partial | g, wg, p.wg =====
        {
            frag_cd aq={0,0,0,0};
#pragma unroll
            for (int i=0;i<4;++i){
                frag_ab a=*(const frag_ab*)(wfb + lm*SX + i*32 + kq);
                aq=__builtin_amdgcn_mfma_f32_16x16x32_bf16(a,pkt[i],aq,0,0,0);
            }
            int n=w*16+lm;
            float s1[4], s3[4];
#pragma unroll
            for(int r=0;r<4;++r){
                s1[r]=aq[r]*aq[r];                     // v_n^2
                float eps = lowhalf ? nb[(m0+r)*SNB+n] : 0.f;
                float gv=fast_tanh(mreg[r]+sreg[r]*eps);
                if (lowhalf) gbuf[(m0+r)*128+n]=gv;
                float kv=kreg[r];
                float wg=(1.f-kv*kv)*gv;
                s3[r]=preg[r]*wg;
            }
#pragma unroll
            for(int msk=1;msk<16;msk<<=1){
#pragma unroll
                for(int r=0;r<4;++r){ s1[r]+=__shfl_xor(s1[r],msk,64); s3[r]+=__shfl_xor(s3[r],msk,64); }
            }
            if (lm==0){
#pragma unroll
                for(int r=0;r<4;++r){ qwp[w*16+m0+r]=s1[r]; pwp[w*16+m0+r]=s3[r]; }
            }
        }
        __syncthreads();
        // ===== Stage E: mask + Euler update (no global store) =====
        {
            for (int idx=tid; idx<RB*128; idx+=512){
                int mr=idx>>7;
                float kn2=0.f, jf2=0.f, kdjg=0.f;
#pragma unroll
                for (int wv=0;wv<8;++wv){
                    kn2 +=knp[wv*16+mr];
                    jf2 +=qwp[wv*16+mr];
                    kdjg+=pwp[wv*16+mr];
                }
                kn2=fmaxf(kn2,0.f); jf2=fmaxf(jf2,0.f);
                float kn=sqrtf(kn2);
                float kn9=kn2*kn2*kn2*kn2*kn;
                float kn10=kn2*kn2*kn2*kn2*kn2;
                float c1=sqrtf(jf2)-ALPHA_C*kn9;
                float c2=kdjg-BETA_C*kn10;
                float mask=((c1>EPSC_C)||(c2<-EPSC_C))?0.5f:1.0f;
                float dx=fbuf[idx]+gbuf[idx];
                float yn=ybuf[idx]+mask*dx*dt;
                ybuf[idx]=yn; xb[mr*SX+(idx&127)]=f2b(yn);
            }
        }
        __syncthreads();
    }
    // epilogue: store final frame (y_STEPS) from ybuf
    {
        size_t ob=(size_t)STEPS*BS*128;
        size_t o0=ob+(size_t)(r0+mr0)*128+n0, o1=ob+(size_t)(r0+mr1)*128+n1;
        if (isf32){ ((float*)out)[o0]=ybuf[tid]; ((float*)out)[o1]=ybuf[tid+512]; }
        else { ((__hip_bfloat16*)out)[o0]=__float2bfloat16(ybuf[tid]);
               ((__hip_bfloat16*)out)[o1]=__float2bfloat16(ybuf[tid+512]); }
    }
}

extern "C" void kernel_launch(void* const* d_in, const int* in_sizes, int n_in,
                              void* d_out, int out_size, void* d_ws, size_t ws_size,
                              hipStream_t stream) {
    Ptrs ps;
    for (int i=0;i<19;++i) ps.p[i]=d_in[3+i];
    const void* tp=d_in[1];
    char* wsb=(char*)d_ws;
    float* bdst=(float*)(wsb+BIAS_OFF_B);

    prep_kernel<<<101,256,0,stream>>>(ps, tp, (short*)wsb, bdst);
    ode_kernel<<<BS/RB,512,96*1024,stream>>>(d_in[0], d_in[2], tp, d_out, wsb);
}